// Round 1
// baseline (254.319 us; speedup 1.0000x reference)
//
#include <hip/hip_runtime.h>
#include <cstdint>
#include <cstddef>

typedef short bf16x8 __attribute__((ext_vector_type(8)));
typedef float f32x4 __attribute__((ext_vector_type(4)));
typedef unsigned short u16x4 __attribute__((ext_vector_type(4)));
typedef unsigned short u16x8 __attribute__((ext_vector_type(8)));

#define MFMA(a,b,c) __builtin_amdgcn_mfma_f32_16x16x32_bf16((a),(b),(c),0,0,0)

__device__ __forceinline__ unsigned short f2bf(float x){
  union { float f; unsigned u; } v; v.f = x;
  unsigned r = v.u + 0x7FFFu + ((v.u >> 16) & 1u);  // RNE
  return (unsigned short)(r >> 16);
}
__device__ __forceinline__ float bf2f(unsigned short b){
  union { unsigned u; float f; } v; v.u = ((unsigned)b) << 16;
  return v.f;
}
// load 8 consecutive fp32, convert to bf16x8 fragment
__device__ __forceinline__ bf16x8 cvtld8(const float* p){
  f32x4 a = *(const f32x4*)p;
  f32x4 b = *(const f32x4*)(p + 4);
  bf16x8 r;
  r[0]=(short)f2bf(a.x); r[1]=(short)f2bf(a.y);
  r[2]=(short)f2bf(a.z); r[3]=(short)f2bf(a.w);
  r[4]=(short)f2bf(b.x); r[5]=(short)f2bf(b.y);
  r[6]=(short)f2bf(b.z); r[7]=(short)f2bf(b.w);
  return r;
}

// ---------------- kernel 0: fp32 weights -> bf16 (wq,wk,wv,wg,wo) ----------
__global__ __launch_bounds__(256) void wcvt_kernel(
    const float* __restrict__ wq, const float* __restrict__ wk,
    const float* __restrict__ wv, const float* __restrict__ wg,
    const float* __restrict__ wo, unsigned short* __restrict__ dst)
{
  const int which = blockIdx.x >> 5;   // 32 blocks per 65536-elem matrix
  const float* s = (which==0)?wq:(which==1)?wk:(which==2)?wv:(which==3)?wg:wo;
  const int off = (blockIdx.x & 31) * 2048 + threadIdx.x * 8;
  f32x4 a = *(const f32x4*)(s + off);
  f32x4 b = *(const f32x4*)(s + off + 4);
  u16x8 r;
  r[0]=f2bf(a.x); r[1]=f2bf(a.y); r[2]=f2bf(a.z); r[3]=f2bf(a.w);
  r[4]=f2bf(b.x); r[5]=f2bf(b.y); r[6]=f2bf(b.z); r[7]=f2bf(b.w);
  *(u16x8*)(dst + (size_t)which*65536 + off) = r;
}

// ---------------- kernel 1: projections q,k,v(g) ---------------------------
// side 0: q_x -> q (scaled, [B,H,Q,D] bf16) and g (sigmoid, [B,Q,H,D] bf16)
// side 1: kv_x -> k ([B,H,K,D] bf16) and v^T ([B,H,D,K] bf16)
__global__ __launch_bounds__(256,2) void proj_kernel(
    const float* __restrict__ q_x, const float* __restrict__ kv_x,
    const unsigned short* __restrict__ wb,   // bf16 weights: wq,wk,wv,wg,wo
    const float* __restrict__ bg,
    unsigned short* __restrict__ qws, unsigned short* __restrict__ kws,
    unsigned short* __restrict__ vTws, unsigned short* __restrict__ gws)
{
  const int tid = threadIdx.x;
  const int w = tid >> 6, lane = tid & 63;
  const int c = lane & 15, qd = lane >> 4;
  const int side = blockIdx.x >> 8;          // 256 row-blocks per side
  const int rb = (blockIdx.x & 255) * 16;    // 16 rows per WG
  const float* X = side ? kv_x : q_x;
  const unsigned short* W0 = wb + (size_t)(side ? 1 : 0) * 65536; // wk : wq
  const unsigned short* W1 = wb + (size_t)(side ? 2 : 3) * 65536; // wv : wg
  const int hdw = w * 64;                    // wave owns 64 output channels

  const f32x4 fz = {0.f,0.f,0.f,0.f};
  f32x4 acc[2][4];
  #pragma unroll
  for (int o=0;o<2;o++)
    #pragma unroll
    for (int mt=0;mt<4;mt++) acc[o][mt] = fz;

  #pragma unroll
  for (int ks = 0; ks < 8; ks++){
    const int ko = ks*32 + qd*8;
    bf16x8 bfrag = cvtld8(X + (size_t)(rb + c)*256 + ko);  // activation rows
    #pragma unroll
    for (int mt = 0; mt < 4; mt++){
      const int hd = hdw + mt*16 + c;
      bf16x8 a0 = *(const bf16x8*)(W0 + (size_t)hd*256 + ko);
      bf16x8 a1 = *(const bf16x8*)(W1 + (size_t)hd*256 + ko);
      acc[0][mt] = MFMA(a0, bfrag, acc[0][mt]);
      acc[1][mt] = MFMA(a1, bfrag, acc[1][mt]);
    }
  }

  const int row = rb + c;
  const int b = row >> 10, rr = row & 1023;
  #pragma unroll
  for (int mt = 0; mt < 4; mt++){
    const int hd0 = hdw + mt*16 + qd*4;
    const int h = hd0 >> 5, d0 = hd0 & 31;
    f32x4 v0 = acc[0][mt], v1 = acc[1][mt];
    if (side == 0){
      const float qs = 0.17677669529663687f;   // 1/sqrt(32)
      u16x4 oq = { f2bf(v0.x*qs), f2bf(v0.y*qs), f2bf(v0.z*qs), f2bf(v0.w*qs) };
      *(u16x4*)(qws + ((size_t)((b*8 + h)*1024 + rr))*32 + d0) = oq;
      f32x4 bg4 = *(const f32x4*)(bg + hd0);
      float g0 = 1.f/(1.f + exp2f(-1.44269504f*(v1.x + bg4.x)));
      float g1 = 1.f/(1.f + exp2f(-1.44269504f*(v1.y + bg4.y)));
      float g2 = 1.f/(1.f + exp2f(-1.44269504f*(v1.z + bg4.z)));
      float g3 = 1.f/(1.f + exp2f(-1.44269504f*(v1.w + bg4.w)));
      u16x4 og = { f2bf(g0), f2bf(g1), f2bf(g2), f2bf(g3) };
      *(u16x4*)(gws + ((size_t)((b*1024 + rr)*8 + h))*32 + d0) = og;
    } else {
      u16x4 ok = { f2bf(v0.x), f2bf(v0.y), f2bf(v0.z), f2bf(v0.w) };
      *(u16x4*)(kws + ((size_t)((b*8 + h)*1024 + rr))*32 + d0) = ok;
      size_t vb = ((size_t)((b*8 + h)*32 + d0))*1024 + rr;   // V^T scatter
      vTws[vb         ] = f2bf(v1.x);
      vTws[vb + 1024  ] = f2bf(v1.y);
      vTws[vb + 2048  ] = f2bf(v1.z);
      vTws[vb + 3072  ] = f2bf(v1.w);
    }
  }
}

// ---------------- kernel 2: flash attention -------------------------------
// WG: (bh, q-block of 64). 4 waves x 16 q-rows. K in 4 chunks of 256.
// Scores computed transposed (rows=keys, col=q-row) so each lane owns one
// q-row's softmax state; P^T round-trips LDS; O^T accumulated in regs.
__global__ __launch_bounds__(256,2) void attn_kernel(
    const float* __restrict__ pair_bias, const float* __restrict__ mask_bias,
    const unsigned short* __restrict__ qws, const unsigned short* __restrict__ kws,
    const unsigned short* __restrict__ vTws, const unsigned short* __restrict__ gws,
    unsigned short* __restrict__ ows)
{
  // LDS: kT 4 planes x 256 keys x 16B = 16384; vT 32 rows x 528B = 16896;
  // pT 4 waves x 16 rows x 528B = 33792.  Total 67072 B -> 2 WG/CU.
  __shared__ __align__(16) unsigned char smem[67072];
  unsigned short* kT = (unsigned short*)smem;
  unsigned short* vT = (unsigned short*)(smem + 16384);
  unsigned short* pT = (unsigned short*)(smem + 33280);

  const int tid = threadIdx.x;
  const int w = tid >> 6, lane = tid & 63;
  const int c = lane & 15, qd = lane >> 4;
  const int bh = blockIdx.x >> 4, qb = blockIdx.x & 15;
  const int b  = bh >> 3, h = bh & 7;
  const int qrow = qb*64 + w*16 + c;

  const bf16x8 qf = *(const bf16x8*)(qws + ((size_t)bh*1024 + qrow)*32 + qd*8);
  const float* pbp = pair_bias + ((size_t)bh*1024 + qrow)*1024;
  const float* mbp = mask_bias + (size_t)b*1024;
  unsigned short* pTw = pT + w*4224;          // 16 rows x 264 ushorts

  const f32x4 fz = {0.f,0.f,0.f,0.f};
  float m_i = -3.0e38f, l_i = 0.f;
  f32x4 accO0 = fz, accO1 = fz;

  for (int kc = 0; kc < 4; kc++){
    const int k0 = kc*256;
    // stage K tile: 4 d-planes x 256 keys x 16B (bank-conflict-free layout)
    #pragma unroll
    for (int i = 0; i < 4; i++){
      const int idx = i*256 + tid;
      const int plane = idx >> 8, key = idx & 255;
      u16x8 t8 = *(const u16x8*)(kws + ((size_t)bh*1024 + k0 + key)*32 + plane*8);
      *(u16x8*)(kT + idx*8) = t8;
    }
    // stage V^T tile: 32 d-rows x 256 keys, row stride 264 ushorts (pad)
    #pragma unroll
    for (int i = 0; i < 4; i++){
      const int idx = i*256 + tid;
      const int d = idx >> 5, kch = idx & 31;
      u16x8 t8 = *(const u16x8*)(vTws + ((size_t)bh*32 + d)*1024 + k0 + kch*8);
      *(u16x8*)(vT + d*264 + kch*8) = t8;
    }
    __syncthreads();

    // pass 1: S^T tiles (16 keys x 16 qrows each), fp32 bias add, log2 scale
    f32x4 sf[16];
    float cmax = -3.0e38f;
    #pragma unroll
    for (int t = 0; t < 16; t++){
      bf16x8 af = *(const bf16x8*)(kT + (qd*256 + t*16 + c)*8);
      f32x4 s = MFMA(af, qf, fz);
      f32x4 pb = *(const f32x4*)(pbp + k0 + t*16 + qd*4);
      f32x4 mb = *(const f32x4*)(mbp + k0 + t*16 + qd*4);
      s = (s + pb + mb) * 1.44269504f;
      sf[t] = s;
      cmax = fmaxf(cmax, fmaxf(fmaxf(s.x, s.y), fmaxf(s.z, s.w)));
    }
    // row (=col c) reduction across the 4 quads
    cmax = fmaxf(cmax, __shfl_xor(cmax, 16));
    cmax = fmaxf(cmax, __shfl_xor(cmax, 32));
    const float m_new = fmaxf(m_i, cmax);
    const float alpha = exp2f(m_i - m_new);
    accO0 *= alpha; accO1 *= alpha;

    // pass 2: exponentiate, pack P^T to LDS
    float rsum = 0.f;
    #pragma unroll
    for (int t = 0; t < 16; t++){
      f32x4 p;
      p.x = exp2f(sf[t].x - m_new);
      p.y = exp2f(sf[t].y - m_new);
      p.z = exp2f(sf[t].z - m_new);
      p.w = exp2f(sf[t].w - m_new);
      rsum += (p.x + p.y) + (p.z + p.w);
      u16x4 pk = { f2bf(p.x), f2bf(p.y), f2bf(p.z), f2bf(p.w) };
      *(u16x4*)(pTw + c*264 + t*16 + qd*4) = pk;
    }
    rsum += __shfl_xor(rsum, 16);
    rsum += __shfl_xor(rsum, 32);
    l_i = l_i*alpha + rsum;
    m_i = m_new;

    // PV: O^T(32xQ16) += V^T(32xKc) * P^T(Kcx16)
    #pragma unroll
    for (int ks = 0; ks < 8; ks++){
      bf16x8 pf = *(const bf16x8*)(pTw + c*264 + ks*32 + qd*8);
      bf16x8 v0 = *(const bf16x8*)(vT + c*264 + ks*32 + qd*8);
      bf16x8 v1 = *(const bf16x8*)(vT + (16 + c)*264 + ks*32 + qd*8);
      accO0 = MFMA(v0, pf, accO0);
      accO1 = MFMA(v1, pf, accO1);
    }
    __syncthreads();
  }

  // epilogue: normalize, gate, store o' bf16 [B,Q,H,D]
  const float inv_l = 1.0f / l_i;
  const size_t obase = (((size_t)b*1024 + qrow)*8 + h)*32;
  {
    u16x4 g4 = *(const u16x4*)(gws + obase + qd*4);
    u16x4 o4 = { f2bf(accO0.x*inv_l*bf2f(g4[0])),
                 f2bf(accO0.y*inv_l*bf2f(g4[1])),
                 f2bf(accO0.z*inv_l*bf2f(g4[2])),
                 f2bf(accO0.w*inv_l*bf2f(g4[3])) };
    *(u16x4*)(ows + obase + qd*4) = o4;
  }
  {
    u16x4 g4 = *(const u16x4*)(gws + obase + 16 + qd*4);
    u16x4 o4 = { f2bf(accO1.x*inv_l*bf2f(g4[0])),
                 f2bf(accO1.y*inv_l*bf2f(g4[1])),
                 f2bf(accO1.z*inv_l*bf2f(g4[2])),
                 f2bf(accO1.w*inv_l*bf2f(g4[3])) };
    *(u16x4*)(ows + obase + 16 + qd*4) = o4;
  }
}

// ---------------- kernel 3: output projection -----------------------------
// out^T tiles: A = wo (m = out channel i), B = o' rows -> float4 stores
__global__ __launch_bounds__(256,2) void oproj_kernel(
    const unsigned short* __restrict__ ows, const unsigned short* __restrict__ wob,
    const float* __restrict__ bo, float* __restrict__ out)
{
  const int tid = threadIdx.x;
  const int w = tid >> 6, lane = tid & 63;
  const int c = lane & 15, qd = lane >> 4;
  const int row0 = blockIdx.x * 16;
  const int i0 = w * 64;

  const f32x4 fz = {0.f,0.f,0.f,0.f};
  f32x4 acc[4] = {fz, fz, fz, fz};
  #pragma unroll
  for (int ks = 0; ks < 8; ks++){
    const int ko = ks*32 + qd*8;
    bf16x8 bfrag = *(const bf16x8*)(ows + (size_t)(row0 + c)*256 + ko);
    #pragma unroll
    for (int mt = 0; mt < 4; mt++){
      bf16x8 afrag = *(const bf16x8*)(wob + (size_t)(i0 + mt*16 + c)*256 + ko);
      acc[mt] = MFMA(afrag, bfrag, acc[mt]);
    }
  }
  #pragma unroll
  for (int mt = 0; mt < 4; mt++){
    const int i = i0 + mt*16 + qd*4;
    f32x4 bo4 = *(const f32x4*)(bo + i);
    f32x4 r = acc[mt] + bo4;
    *(f32x4*)(out + (size_t)(row0 + c)*256 + i) = r;
  }
}

extern "C" void kernel_launch(void* const* d_in, const int* in_sizes, int n_in,
                              void* d_out, int out_size, void* d_ws, size_t ws_size,
                              hipStream_t stream) {
  const float* q_x       = (const float*)d_in[0];
  const float* kv_x      = (const float*)d_in[1];
  const float* mask_bias = (const float*)d_in[2];
  const float* pair_bias = (const float*)d_in[3];
  const float* wq        = (const float*)d_in[4];
  const float* wk        = (const float*)d_in[5];
  const float* wv        = (const float*)d_in[6];
  const float* wg        = (const float*)d_in[7];
  const float* bg        = (const float*)d_in[8];
  const float* wo        = (const float*)d_in[9];
  const float* bo        = (const float*)d_in[10];

  unsigned short* ws  = (unsigned short*)d_ws;
  unsigned short* qws  = ws;                       // [B,H,Q,D]  1M
  unsigned short* kws  = ws + (1u<<20);            // [B,H,K,D]  1M
  unsigned short* vTws = ws + 2*(1u<<20);          // [B,H,D,K]  1M
  unsigned short* gws  = ws + 3*(1u<<20);          // [B,Q,H,D]  1M
  unsigned short* ows  = ws + 4*(1u<<20);          // [B,Q,H*D]  1M
  unsigned short* wb   = ws + 5*(1u<<20);          // 5 x 65536 bf16 weights

  wcvt_kernel<<<160, 256, 0, stream>>>(wq, wk, wv, wg, wo, wb);
  proj_kernel<<<512, 256, 0, stream>>>(q_x, kv_x, wb, bg, qws, kws, vTws, gws);
  attn_kernel<<<512, 256, 0, stream>>>(pair_bias, mask_bias, qws, kws, vTws, gws, ows);
  oproj_kernel<<<256, 256, 0, stream>>>(ows, wb + 4*65536, bo, (float*)d_out);
}